// Round 6
// baseline (629.999 us; speedup 1.0000x reference)
//
#include <hip/hip_runtime.h>
#include <cstdint>
#include <cstddef>

// ---------- types ----------
typedef __attribute__((ext_vector_type(8))) __bf16 bf16x8;
typedef __attribute__((ext_vector_type(4))) float f32x4;
typedef __attribute__((ext_vector_type(8))) unsigned short us8;
typedef __attribute__((ext_vector_type(4))) unsigned short us4;

__device__ inline unsigned short f2bf(float f) {
    unsigned int u = __float_as_uint(f);
    u += 0x7fffu + ((u >> 16) & 1u);   // RNE
    return (unsigned short)(u >> 16);
}

// pack two f32 -> two bf16 by truncation (1 instr); |rel err| < 2^-8, fine for P
__device__ inline unsigned int pkbf_t(float hi, float lo) {
    return __builtin_amdgcn_perm(__float_as_uint(hi), __float_as_uint(lo), 0x07060302u);
}

__device__ inline void async_copy16(const void* g, void* l) {
    __builtin_amdgcn_global_load_lds(
        (const __attribute__((address_space(1))) unsigned int*)g,
        (__attribute__((address_space(3))) unsigned int*)l, 16, 0, 0);
}

// ---------- fp32 -> bf16 convert ----------
__global__ __launch_bounds__(256) void cvt_bf16(const float* __restrict__ in,
                                                unsigned short* __restrict__ out, int n4) {
    int i = blockIdx.x * 256 + threadIdx.x;
    if (i < n4) {
        float4 v = ((const float4*)in)[i];
        us4 o;
        o[0] = f2bf(v.x); o[1] = f2bf(v.y); o[2] = f2bf(v.z); o[3] = f2bf(v.w);
        ((us4*)out)[i] = o;
    }
}

// ---------- layernorm (fp32 in, bf16 out) ----------
__global__ __launch_bounds__(256) void ln_bf16(const float* __restrict__ X,
                                               const float* __restrict__ g,
                                               const float* __restrict__ b,
                                               unsigned short* __restrict__ out) {
    int row = blockIdx.x;
    int t = threadIdx.x;
    float4 v = ((const float4*)(X + (size_t)row * 1024))[t];
    float s  = v.x + v.y + v.z + v.w;
    float s2 = v.x * v.x + v.y * v.y + v.z * v.z + v.w * v.w;
#pragma unroll
    for (int m = 1; m < 64; m <<= 1) {
        s  += __shfl_xor(s, m, 64);
        s2 += __shfl_xor(s2, m, 64);
    }
    __shared__ float red[8];
    int w = t >> 6, l = t & 63;
    if (l == 0) { red[w] = s; red[4 + w] = s2; }
    __syncthreads();
    s  = red[0] + red[1] + red[2] + red[3];
    s2 = red[4] + red[5] + red[6] + red[7];
    float mu  = s * (1.0f / 1024.0f);
    float var = s2 * (1.0f / 1024.0f) - mu * mu;
    float rs  = rsqrtf(var + 1e-5f);
    int c = t * 4;
    float4 gv = *(const float4*)(g + c);
    float4 bv = *(const float4*)(b + c);
    us4 o;
    o[0] = f2bf((v.x - mu) * rs * gv.x + bv.x);
    o[1] = f2bf((v.y - mu) * rs * gv.y + bv.y);
    o[2] = f2bf((v.z - mu) * rs * gv.z + bv.z);
    o[3] = f2bf((v.w - mu) * rs * gv.w + bv.w);
    *(us4*)(out + (size_t)row * 1024 + c) = o;
}

// ---------- NT GEMM v4: 256xBN tile, BK=64, 8 waves, faithful 8-phase ----------
// C[M,N] = A[M,K] @ B[N,K]^T, bf16 in, fp32 acc.
// Phase = { ds_reads (pre-barrier) ; s_barrier ; lgkmcnt(0)+sched_barrier ;
//           setprio(1) ; 16 MFMA ; setprio(0) }.  16 MFMA/phase in both variants.
// Boundary = { barrier ; STAGE(kt+2 -> freed buf) ; vmcnt(LOADS) waits kt+1 ;
//              barrier }.  Counted vmcnt, never 0 in steady state.
// T2 XOR swizzle both-sides (linear LDS dest, inverse-swizzled global src,
// swizzled ds_read) -- verified 0 bank conflicts in round 4.
// EPI: 1 gelu(bias)->bf16 ; 2 bias+resid->fp32 ; 6 fused QKV epilogue.
template <int EPI, int BNt>
__global__ __launch_bounds__(512, 2) void gemm_nt(const unsigned short* __restrict__ A,
                                                  const unsigned short* __restrict__ B,
                                                  const float* __restrict__ bias,
                                                  const float* __restrict__ resid,
                                                  void* __restrict__ Cout, int N, int K) {
    constexpr int NF = BNt / 64;             // n-frags per wave (4 or 2)
    constexpr int MH = (BNt == 256) ? 2 : 1; // m-halves per kc (phase split)
    constexpr int MF = 8 / MH;               // m-frags per phase (4 or 8)
    constexpr int NB = BNt / 64;             // B staging chunks per thread
    constexpr int WTN = BNt / 4;             // wave N-tile

    __shared__ __align__(16) unsigned short As[2][256 * 64];
    __shared__ __align__(16) unsigned short Bs[2][BNt * 64];
    const int tid = threadIdx.x;
    const int lane = tid & 63, w = tid >> 6;
    const int quad = lane >> 4, l16 = lane & 15;
    const int wr = w >> 2, wc = w & 3;       // 2x4 wave grid
    const int sw = l16 & 7;

    // XCD-chunked swizzle (all grids have nwg % 8 == 0)
    const int gx = gridDim.x;
    const int nwg = gx * gridDim.y;
    int wg = blockIdx.y * gx + blockIdx.x;
    if (!(nwg & 7)) wg = (wg & 7) * (nwg >> 3) + (wg >> 3);
    const size_t bm = (size_t)(wg / gx) * 256;
    const size_t bn = (size_t)(wg % gx) * BNt;

    // staging sources: lds chunk c covers 16B at linear offset c*16; content is
    // tile[row][chunk ^ (row&7)] (involution -> reads un-swizzle it).
    const unsigned short* pA[4];
    const unsigned short* pB[4];
#pragma unroll
    for (int j = 0; j < 4; j++) {
        int c = j * 512 + tid;
        int row = c >> 3;
        int sc = (c & 7) ^ (row & 7);
        pA[j] = A + (bm + row) * (size_t)K + sc * 8;
    }
#pragma unroll
    for (int j = 0; j < NB; j++) {
        int c = j * 512 + tid;
        int row = c >> 3;
        int sc = (c & 7) ^ (row & 7);
        pB[j] = B + (bn + row) * (size_t)K + sc * 8;
    }

#define STAGE(buf, kt)                                                        \
    {                                                                         \
        const int koff = (kt)*64;                                             \
        _Pragma("unroll") for (int j = 0; j < 4; j++)                         \
            async_copy16(pA[j] + koff, &As[buf][(j * 512 + tid) * 8]);        \
        _Pragma("unroll") for (int j = 0; j < NB; j++)                        \
            async_copy16(pB[j] + koff, &Bs[buf][(j * 512 + tid) * 8]);        \
    }
#define WAIT_LOADS()                                                          \
    {                                                                         \
        if constexpr (NB == 4) asm volatile("s_waitcnt vmcnt(8)" ::: "memory"); \
        else                   asm volatile("s_waitcnt vmcnt(6)" ::: "memory"); \
    }

    f32x4 acc[8][NF];
#pragma unroll
    for (int i = 0; i < 8; i++)
#pragma unroll
        for (int j = 0; j < NF; j++) acc[i][j] = (f32x4){0.f, 0.f, 0.f, 0.f};

    const int nk = K / 64;   // >= 16 for all our shapes

    STAGE(0, 0);
    STAGE(1, 1);
    WAIT_LOADS();                                  // tile 0 landed; tile 1 in flight
    asm volatile("s_barrier" ::: "memory");

    for (int kt = 0; kt < nk; ++kt) {
        const int cur = kt & 1;
        const unsigned short* Asr = As[cur];
        const unsigned short* Bsr = Bs[cur];
#pragma unroll
        for (int kc = 0; kc < 2; kc++) {
            bf16x8 bfr[NF];
#pragma unroll
            for (int nf = 0; nf < NF; nf++) {
                int row = wc * WTN + nf * 16 + l16;
                bfr[nf] = *(const bf16x8*)&Bsr[row * 64 + (((kc * 4 + quad) ^ sw) << 3)];
            }
#pragma unroll
            for (int mh = 0; mh < MH; mh++) {
                bf16x8 af[MF];
#pragma unroll
                for (int i = 0; i < MF; i++) {
                    int row = wr * 128 + (mh * MF + i) * 16 + l16;
                    af[i] = *(const bf16x8*)&Asr[row * 64 + (((kc * 4 + quad) ^ sw) << 3)];
                }
                // reads issued pre-barrier: they overlap other waves' MFMA phase
                asm volatile("s_barrier" ::: "memory");
                asm volatile("s_waitcnt lgkmcnt(0)" ::: "memory");
                __builtin_amdgcn_sched_barrier(0);
                __builtin_amdgcn_s_setprio(1);
#pragma unroll
                for (int i = 0; i < MF; i++)
#pragma unroll
                    for (int nf = 0; nf < NF; nf++)
                        acc[mh * MF + i][nf] = __builtin_amdgcn_mfma_f32_16x16x32_bf16(
                            af[i], bfr[nf], acc[mh * MF + i][nf], 0, 0, 0);
                __builtin_amdgcn_s_setprio(0);
            }
        }
        // K-tile boundary: all waves' reads of buf[cur] drained (own lgkmcnt(0)
        // before their last MFMA) before anyone passes this barrier.
        asm volatile("s_barrier" ::: "memory");
        if (kt + 2 < nk) {
            STAGE(cur, kt + 2);          // into just-freed buf; in flight: kt+1, kt+2
            WAIT_LOADS();                // retire exactly tile kt+1; kt+2 stays flying
        } else if (kt + 1 < nk) {
            asm volatile("s_waitcnt vmcnt(0)" ::: "memory");   // drain last tile
        }
        asm volatile("s_barrier" ::: "memory");
    }
#undef STAGE
#undef WAIT_LOADS

#pragma unroll
    for (int mf = 0; mf < 8; mf++) {
#pragma unroll
        for (int nf = 0; nf < NF; nf++) {
#pragma unroll
            for (int rr = 0; rr < 4; rr++) {
                size_t row = bm + wr * 128 + mf * 16 + quad * 4 + rr;
                size_t col = bn + wc * WTN + nf * 16 + l16;
                float v = acc[mf][nf][rr] + bias[col];
                if (EPI == 1) {
                    v = 0.5f * v * (1.0f + erff(v * 0.70710678118654752f));
                    ((unsigned short*)Cout)[row * N + col] = f2bf(v);
                } else if (EPI == 2) {
                    ((float*)Cout)[row * N + col] = v + resid[row * N + col];
                } else if (EPI == 6) {
                    int sel = (int)(bn >> 10);
                    if (sel == 0) {
                        ((unsigned short*)Cout)[row * 1024 + col] =
                            f2bf(v * 0.18033688011112042f);  // 0.125*log2(e)
                    } else {
                        int key = (int)row & 2047;
                        int bh  = (((int)row >> 11) << 4) | (((int)col >> 6) & 15);
                        int dh  = (int)col & 63;
                        size_t addr;
                        if (sel == 1)
                            addr = 8388608 + (size_t)bh * 131072 +
                                   (size_t)(key >> 6) * 4096 + (size_t)(key & 63) * 64 +
                                   ((((dh >> 3) ^ (key & 7))) << 3) + (dh & 7);
                        else
                            addr = 16777216 + (size_t)bh * 131072 +
                                   (size_t)(key >> 6) * 4096 + (size_t)dh * 64 +
                                   (((((key >> 3) & 7) ^ (dh & 7))) << 3) + (key & 7);
                        ((unsigned short*)Cout)[addr] = f2bf(v);
                    }
                }
            }
        }
    }
}

// ---------- flash attention v4b: + bh-grouped XCD swizzle ----------
// grid: 1024 blocks; bh = bid & 63, qblk = bid >> 6  => the 16 qblocks of a bh
// land on indices == bh (mod 64), i.e. the SAME XCD -> K/V stay L2-local.
// Pipeline unchanged from v4 (verified): dbuf K, late-prefetch V, counted vmcnt.
__global__ __launch_bounds__(256) void attn_kernel(const unsigned short* __restrict__ Q,
                                                   const unsigned short* __restrict__ Kb,
                                                   const unsigned short* __restrict__ Vtb,
                                                   unsigned short* __restrict__ O) {
    const int bh   = blockIdx.x & 63;
    const int qblk = blockIdx.x >> 6;
    const int b = bh >> 4, h = bh & 15;
    const int tid = threadIdx.x, lane = tid & 63, w = tid >> 6;
    const int quad = lane >> 4, l16 = lane & 15;
    const int sw = l16 & 7;

    __shared__ __align__(16) unsigned short smem[20480];   // 40 KB
    unsigned short* Vts = smem + 8192;                     // [64 dh][swz 64 key]
    unsigned short* Psw = smem + 12288 + w * 2048;         // per-wave [32 q][swz 64 key]

    const size_t qrow0 = (size_t)b * 2048 + (size_t)qblk * 128 + w * 32;
    const int hcol = h * 64;

    // Q fragment loads first: oldest vmem ops, drained by the first vmcnt(4)
    bf16x8 qfr[2][2];
#pragma unroll
    for (int qf = 0; qf < 2; qf++)
#pragma unroll
        for (int kp = 0; kp < 2; kp++)
            qfr[qf][kp] = *(const bf16x8*)(Q + (qrow0 + qf * 16 + l16) * 1024 +
                                           hcol + kp * 32 + quad * 8);

    const unsigned short* ksrc = Kb  + (size_t)bh * 131072;
    const unsigned short* vsrc = Vtb + (size_t)bh * 131072;

    // prologue: stage K(0) -> buf0, V(0) -> Vts
    async_copy16(ksrc + tid * 8,        smem + tid * 8);
    async_copy16(ksrc + 2048 + tid * 8, smem + 2048 + tid * 8);
    async_copy16(vsrc + tid * 8,        Vts + tid * 8);
    async_copy16(vsrc + 2048 + tid * 8, Vts + 2048 + tid * 8);

    f32x4 acc[4][2];
#pragma unroll
    for (int df = 0; df < 4; df++)
#pragma unroll
        for (int qf = 0; qf < 2; qf++) acc[df][qf] = (f32x4){0.f, 0.f, 0.f, 0.f};
    float l_[2] = {0.f, 0.f};   // in-lane partial sums; cross-quad reduce at end

    for (int kt = 0; kt < 32; ++kt) {
        unsigned short* Ks = (kt & 1) ? (smem + 4096) : smem;   // current K buffer
        if (kt < 31) {
            unsigned short* Kd = (kt & 1) ? smem : (smem + 4096);
            const unsigned short* kg = ksrc + (size_t)(kt + 1) * 4096;
            async_copy16(kg + tid * 8,        Kd + tid * 8);
            async_copy16(kg + 2048 + tid * 8, Kd + 2048 + tid * 8);
            asm volatile("s_waitcnt vmcnt(4)" ::: "memory");    // K(kt) landed
        } else {
            asm volatile("s_waitcnt vmcnt(2)" ::: "memory");    // K(31) landed
        }
        asm volatile("s_barrier" ::: "memory");

        // S^T[64 key][32 q] = K Q^T
        f32x4 s[4][2];
#pragma unroll
        for (int mf = 0; mf < 4; mf++)
#pragma unroll
            for (int qf = 0; qf < 2; qf++) s[mf][qf] = (f32x4){0.f, 0.f, 0.f, 0.f};
        __builtin_amdgcn_s_setprio(1);
#pragma unroll
        for (int kp = 0; kp < 2; kp++) {
#pragma unroll
            for (int mf = 0; mf < 4; mf++) {
                bf16x8 kf = *(const bf16x8*)&Ks[(mf * 16 + l16) * 64 +
                                                (((kp * 4 + quad) ^ sw) << 3)];
#pragma unroll
                for (int qf = 0; qf < 2; qf++)
                    s[mf][qf] = __builtin_amdgcn_mfma_f32_16x16x32_bf16(kf, qfr[qf][kp],
                                                                        s[mf][qf], 0, 0, 0);
            }
        }
        __builtin_amdgcn_s_setprio(0);

        // p = exp2(s); accumulate in-lane row sums; trunc-pack into Psw
#pragma unroll
        for (int mf = 0; mf < 4; mf++)
#pragma unroll
            for (int qf = 0; qf < 2; qf++) {
                float e0 = exp2f(s[mf][qf][0]);
                float e1 = exp2f(s[mf][qf][1]);
                float e2 = exp2f(s[mf][qf][2]);
                float e3 = exp2f(s[mf][qf][3]);
                l_[qf] += (e0 + e1) + (e2 + e3);
                *(uint2*)&Psw[(qf * 16 + l16) * 64 +
                              (((mf * 2 + (quad >> 1)) ^ sw) << 3) + ((quad & 1) << 2)] =
                    make_uint2(pkbf_t(e1, e0), pkbf_t(e3, e2));
            }
        asm volatile("s_waitcnt lgkmcnt(0)" ::: "memory");

        if (kt < 31) {
            asm volatile("s_waitcnt vmcnt(2)" ::: "memory");    // V(kt) landed
        } else {
            asm volatile("s_waitcnt vmcnt(0)" ::: "memory");
        }
        asm volatile("s_barrier" ::: "memory");

        // out^T[64 dh][32 q] += V^T P^T
        __builtin_amdgcn_s_setprio(1);
#pragma unroll
        for (int kp = 0; kp < 2; kp++) {
            bf16x8 pf[2];
#pragma unroll
            for (int qf = 0; qf < 2; qf++)
                pf[qf] = *(const bf16x8*)&Psw[(qf * 16 + l16) * 64 +
                                              (((kp * 4 + quad) ^ sw) << 3)];
#pragma unroll
            for (int df = 0; df < 4; df++) {
                bf16x8 vf = *(const bf16x8*)&Vts[(df * 16 + l16) * 64 +
                                                 (((kp * 4 + quad) ^ sw) << 3)];
#pragma unroll
                for (int qf = 0; qf < 2; qf++)
                    acc[df][qf] = __builtin_amdgcn_mfma_f32_16x16x32_bf16(vf, pf[qf],
                                                                          acc[df][qf], 0, 0, 0);
            }
        }
        __builtin_amdgcn_s_setprio(0);

        asm volatile("s_barrier" ::: "memory");
        if (kt < 31) {
            const unsigned short* vg = vsrc + (size_t)(kt + 1) * 4096;
            async_copy16(vg + tid * 8,        Vts + tid * 8);
            async_copy16(vg + 2048 + tid * 8, Vts + 2048 + tid * 8);
        }
    }

    // final row-sum reduction across quads (keys were split 4 ways)
#pragma unroll
    for (int qf = 0; qf < 2; qf++) {
        l_[qf] += __shfl_xor(l_[qf], 16, 64);
        l_[qf] += __shfl_xor(l_[qf], 32, 64);
    }

    // epilogue: normalize, transpose through LDS, coalesced bf16 store
    __syncthreads();
    float inv[2] = {1.f / l_[0], 1.f / l_[1]};
    unsigned short* Ls = smem;   // [64 dh][128 q] stride 130
#pragma unroll
    for (int df = 0; df < 4; df++)
#pragma unroll
        for (int qf = 0; qf < 2; qf++)
#pragma unroll
            for (int r = 0; r < 4; r++) {
                int dh = df * 16 + quad * 4 + r;
                int q  = w * 32 + qf * 16 + l16;
                Ls[dh * 130 + q] =
                    (unsigned short)((__float_as_uint(acc[df][qf][r] * inv[qf]) + 0x8000u) >> 16);
            }
    __syncthreads();
    int q = tid >> 1, dh0 = (tid & 1) * 32;
    size_t obase = ((size_t)b * 2048 + (size_t)qblk * 128 + q) * 1024 + hcol + dh0;
#pragma unroll
    for (int c = 0; c < 4; c++) {
        us8 o;
#pragma unroll
        for (int j = 0; j < 8; j++) o[j] = Ls[(dh0 + c * 8 + j) * 130 + q];
        *(us8*)(O + obase + c * 8) = o;
    }
}

// ---------- launch ----------
extern "C" void kernel_launch(void* const* d_in, const int* in_sizes, int n_in,
                              void* d_out, int out_size, void* d_ws, size_t ws_size,
                              hipStream_t stream) {
    const float* x     = (const float*)d_in[0];
    const float* ln1_g = (const float*)d_in[1];
    const float* ln1_b = (const float*)d_in[2];
    const float* ln2_g = (const float*)d_in[3];
    const float* ln2_b = (const float*)d_in[4];
    const float* wq = (const float*)d_in[5];
    const float* bq = (const float*)d_in[6];
    const float* wk = (const float*)d_in[7];
    const float* bk = (const float*)d_in[8];
    const float* wv = (const float*)d_in[9];
    const float* bv = (const float*)d_in[10];
    const float* wo = (const float*)d_in[11];
    const float* bo = (const float*)d_in[12];
    const float* w1 = (const float*)d_in[13];
    const float* b1 = (const float*)d_in[14];
    const float* w2 = (const float*)d_in[15];
    const float* b2 = (const float*)d_in[16];

    const size_t MB = 1u << 20;
    char* ws = (char*)d_ws;
    unsigned short* wqkvb = (unsigned short*)(ws + 0 * MB);   // [3072,1024] bf16, 6 MB
    unsigned short* wob  = (unsigned short*)(ws + 6 * MB);
    unsigned short* w1b  = (unsigned short*)(ws + 8 * MB);
    unsigned short* w2b  = (unsigned short*)(ws + 16 * MB);
    unsigned short* hb   = (unsigned short*)(ws + 24 * MB);   // LN1 out, later attn out
    unsigned short* qkvb = (unsigned short*)(ws + 40 * MB);   // Q | K-blocked | V^T-blocked
    unsigned short* qb   = qkvb;
    unsigned short* kblk = qkvb + 8388608;
    unsigned short* vtblk= qkvb + 16777216;
    float*          x1   = (float*)(ws + 56 * MB);            // overlays kblk+vtblk (dead)
    unsigned short* h2b  = (unsigned short*)(ws + 40 * MB);   // overlays qb (dead)
    unsigned short* ff1b = (unsigned short*)(ws + 88 * MB);   // 64 MB
    float*          bqkv = (float*)(ws + 151 * MB);           // [3072] fp32 (inside ff1b, dead then)

    const int D = 1024, FF = 4096, Mrows = 8192;

    cvt_bf16<<<(D * D / 4 + 255) / 256, 256, 0, stream>>>(wq, wqkvb,               D * D / 4);
    cvt_bf16<<<(D * D / 4 + 255) / 256, 256, 0, stream>>>(wk, wqkvb + D * D,       D * D / 4);
    cvt_bf16<<<(D * D / 4 + 255) / 256, 256, 0, stream>>>(wv, wqkvb + 2 * D * D,   D * D / 4);
    cvt_bf16<<<(D * D / 4 + 255) / 256, 256, 0, stream>>>(wo, wob, D * D / 4);
    cvt_bf16<<<(FF * D / 4 + 255) / 256, 256, 0, stream>>>(w1, w1b, FF * D / 4);
    cvt_bf16<<<(FF * D / 4 + 255) / 256, 256, 0, stream>>>(w2, w2b, FF * D / 4);

    hipMemcpyAsync(bqkv,            bq, D * sizeof(float), hipMemcpyDeviceToDevice, stream);
    hipMemcpyAsync(bqkv + D,        bk, D * sizeof(float), hipMemcpyDeviceToDevice, stream);
    hipMemcpyAsync(bqkv + 2 * D,    bv, D * sizeof(float), hipMemcpyDeviceToDevice, stream);

    ln_bf16<<<Mrows, 256, 0, stream>>>(x, ln1_g, ln1_b, hb);

    // fused QKV projection: 256x256 tile -> grid 12x32 = 384 wgs
    dim3 gQKV(3 * D / 256, Mrows / 256);
    gemm_nt<6, 256><<<gQKV, 512, 0, stream>>>(hb, wqkvb, bqkv, nullptr, qkvb, D, D);

    attn_kernel<<<1024, 256, 0, stream>>>(qb, kblk, vtblk, hb);

    // WO + resid: 256x128 tile -> grid 8x32 = 256 wgs (full device)
    dim3 gD(D / 128, Mrows / 256);
    gemm_nt<2, 128><<<gD, 512, 0, stream>>>(hb, wob, bo, x, x1, D, D);

    ln_bf16<<<Mrows, 256, 0, stream>>>(x1, ln2_g, ln2_b, h2b);

    // FF1+gelu: 256x256 tile -> grid 16x32 = 512 wgs
    dim3 gFF(FF / 256, Mrows / 256);
    gemm_nt<1, 256><<<gFF, 512, 0, stream>>>(h2b, w1b, b1, nullptr, ff1b, FF, D);

    // FF2 + resid: 256x128 tile -> grid 8x32 = 256 wgs
    gemm_nt<2, 128><<<gD, 512, 0, stream>>>(ff1b, w2b, b2, x1, (float*)d_out, D, FF);
}

// Round 7
// 616.091 us; speedup vs baseline: 1.0226x; 1.0226x over previous
//
#include <hip/hip_runtime.h>
#include <cstdint>
#include <cstddef>

// ---------- types ----------
typedef __attribute__((ext_vector_type(8))) __bf16 bf16x8;
typedef __attribute__((ext_vector_type(4))) float f32x4;
typedef __attribute__((ext_vector_type(8))) unsigned short us8;
typedef __attribute__((ext_vector_type(4))) unsigned short us4;

__device__ inline unsigned short f2bf(float f) {
    unsigned int u = __float_as_uint(f);
    u += 0x7fffu + ((u >> 16) & 1u);   // RNE
    return (unsigned short)(u >> 16);
}

__device__ inline float bf2f(unsigned short u) {
    return __uint_as_float(((unsigned int)u) << 16);
}

// pack two f32 -> two bf16 by truncation (1 instr); |rel err| < 2^-8, fine for P
__device__ inline unsigned int pkbf_t(float hi, float lo) {
    return __builtin_amdgcn_perm(__float_as_uint(hi), __float_as_uint(lo), 0x07060302u);
}

__device__ inline void async_copy16(const void* g, void* l) {
    __builtin_amdgcn_global_load_lds(
        (const __attribute__((address_space(1))) unsigned int*)g,
        (__attribute__((address_space(3))) unsigned int*)l, 16, 0, 0);
}

// ---------- fp32 -> bf16 convert ----------
__global__ __launch_bounds__(256) void cvt_bf16(const float* __restrict__ in,
                                                unsigned short* __restrict__ out, int n4) {
    int i = blockIdx.x * 256 + threadIdx.x;
    if (i < n4) {
        float4 v = ((const float4*)in)[i];
        us4 o;
        o[0] = f2bf(v.x); o[1] = f2bf(v.y); o[2] = f2bf(v.z); o[3] = f2bf(v.w);
        ((us4*)out)[i] = o;
    }
}

// ---------- layernorm (fp32 in, bf16 out) ----------
__global__ __launch_bounds__(256) void ln_bf16(const float* __restrict__ X,
                                               const float* __restrict__ g,
                                               const float* __restrict__ b,
                                               unsigned short* __restrict__ out) {
    int row = blockIdx.x;
    int t = threadIdx.x;
    float4 v = ((const float4*)(X + (size_t)row * 1024))[t];
    float s  = v.x + v.y + v.z + v.w;
    float s2 = v.x * v.x + v.y * v.y + v.z * v.z + v.w * v.w;
#pragma unroll
    for (int m = 1; m < 64; m <<= 1) {
        s  += __shfl_xor(s, m, 64);
        s2 += __shfl_xor(s2, m, 64);
    }
    __shared__ float red[8];
    int w = t >> 6, l = t & 63;
    if (l == 0) { red[w] = s; red[4 + w] = s2; }
    __syncthreads();
    s  = red[0] + red[1] + red[2] + red[3];
    s2 = red[4] + red[5] + red[6] + red[7];
    float mu  = s * (1.0f / 1024.0f);
    float var = s2 * (1.0f / 1024.0f) - mu * mu;
    float rs  = rsqrtf(var + 1e-5f);
    int c = t * 4;
    float4 gv = *(const float4*)(g + c);
    float4 bv = *(const float4*)(b + c);
    us4 o;
    o[0] = f2bf((v.x - mu) * rs * gv.x + bv.x);
    o[1] = f2bf((v.y - mu) * rs * gv.y + bv.y);
    o[2] = f2bf((v.z - mu) * rs * gv.z + bv.z);
    o[3] = f2bf((v.w - mu) * rs * gv.w + bv.w);
    *(us4*)(out + (size_t)row * 1024 + c) = o;
}

// ---------- NT GEMM (round-5 verified best): 128x128, BK=32, dist-2 pipeline ----------
// triple-buffered LDS (48 KB, 3 blocks/CU); at iter kt: vmcnt(8) waits tile kt
// (issued 2 iters ago), barrier, stage kt+2 into buf[(kt+2)%3], ds_read buf[kt%3],
// MFMA. One barrier per K-step. XCD-chunked block swizzle.
// EPI: 1 gelu(bias)->bf16 ; 2 bias+resid->fp32 ; 6 fused QKV epilogue.
#define BM 128
#define BN 128
#define BK 32

template <int EPI>
__global__ __launch_bounds__(256) void gemm_nt(const unsigned short* __restrict__ A,
                                               const unsigned short* __restrict__ B,
                                               const float* __restrict__ bias,
                                               const float* __restrict__ resid,
                                               void* __restrict__ Cout, int N, int K) {
    __shared__ __align__(16) unsigned short As[3][BM * BK];
    __shared__ __align__(16) unsigned short Bs[3][BN * BK];
    const int tid = threadIdx.x;
    const int lane = tid & 63, w = tid >> 6;
    const int quad = lane >> 4, l16 = lane & 15;
    const int wr = w >> 1, wc = w & 1;

    const int gx = gridDim.x;
    const int nwg = gx * gridDim.y;
    int wg = blockIdx.y * gx + blockIdx.x;
    if (!(nwg & 7)) wg = (wg & 7) * (nwg >> 3) + (wg >> 3);
    const size_t bm = (size_t)(wg / gx) * BM;
    const size_t bn = (size_t)(wg % gx) * BN;

#define STAGE(buf, kt)                                                        \
    {                                                                         \
        const int koff = (kt)*BK;                                             \
        _Pragma("unroll") for (int i = 0; i < 2; i++) {                       \
            int e = (i * 256 + tid) * 8;                                      \
            int r = e >> 5, c = e & 31;                                       \
            async_copy16(A + (bm + r) * K + koff + c, &As[buf][e]);           \
            async_copy16(B + (bn + r) * K + koff + c, &Bs[buf][e]);           \
        }                                                                     \
    }

    f32x4 acc[4][4];
#pragma unroll
    for (int i = 0; i < 4; i++)
#pragma unroll
        for (int j = 0; j < 4; j++) acc[i][j] = (f32x4){0.f, 0.f, 0.f, 0.f};

    const int nk = K / BK;

    STAGE(0, 0);
    STAGE(1, 1);

    for (int kt = 0; kt < nk; ++kt) {
        const int cur = kt % 3;
        if (kt + 1 < nk) {
            asm volatile("s_waitcnt vmcnt(8)" ::: "memory");
        } else {
            asm volatile("s_waitcnt vmcnt(0)" ::: "memory");
        }
        asm volatile("s_barrier" ::: "memory");

        if (kt + 2 < nk) {
            const int nxt2 = (kt + 2) % 3;
            STAGE(nxt2, kt + 2);
        }

        bf16x8 af[4], bfr[4];
#pragma unroll
        for (int mt = 0; mt < 4; mt++)
            af[mt] = *(const bf16x8*)&As[cur][(wr * 64 + mt * 16 + l16) * BK + quad * 8];
#pragma unroll
        for (int nt = 0; nt < 4; nt++)
            bfr[nt] = *(const bf16x8*)&Bs[cur][(wc * 64 + nt * 16 + l16) * BK + quad * 8];

        __builtin_amdgcn_s_setprio(1);
#pragma unroll
        for (int mt = 0; mt < 4; mt++)
#pragma unroll
            for (int nt = 0; nt < 4; nt++)
                acc[mt][nt] = __builtin_amdgcn_mfma_f32_16x16x32_bf16(af[mt], bfr[nt],
                                                                      acc[mt][nt], 0, 0, 0);
        __builtin_amdgcn_s_setprio(0);
        __builtin_amdgcn_sched_barrier(0);
    }
#undef STAGE

#pragma unroll
    for (int mt = 0; mt < 4; mt++) {
#pragma unroll
        for (int nt = 0; nt < 4; nt++) {
#pragma unroll
            for (int r = 0; r < 4; r++) {
                size_t row = bm + wr * 64 + mt * 16 + quad * 4 + r;
                size_t col = bn + wc * 64 + nt * 16 + l16;
                float v = acc[mt][nt][r] + bias[col];
                if (EPI == 1) {
                    v = 0.5f * v * (1.0f + erff(v * 0.70710678118654752f));
                    ((unsigned short*)Cout)[row * N + col] = f2bf(v);
                } else if (EPI == 2) {
                    ((float*)Cout)[row * N + col] = v + resid[row * N + col];
                } else if (EPI == 6) {
                    int sel = (int)(bn >> 10);
                    if (sel == 0) {
                        ((unsigned short*)Cout)[row * 1024 + col] =
                            f2bf(v * 0.18033688011112042f);  // 0.125*log2(e)
                    } else {
                        int key = (int)row & 2047;
                        int bh  = (((int)row >> 11) << 4) | (((int)col >> 6) & 15);
                        int dh  = (int)col & 63;
                        size_t addr;
                        if (sel == 1)
                            addr = 8388608 + (size_t)bh * 131072 +
                                   (size_t)(key >> 6) * 4096 + (size_t)(key & 63) * 64 +
                                   ((((dh >> 3) ^ (key & 7))) << 3) + (dh & 7);
                        else
                            addr = 16777216 + (size_t)bh * 131072 +
                                   (size_t)(key >> 6) * 4096 + (size_t)dh * 64 +
                                   (((((key >> 3) & 7) ^ (dh & 7))) << 3) + (key & 7);
                        ((unsigned short*)Cout)[addr] = f2bf(v);
                    }
                }
            }
        }
    }
}

// ---------- flash attention v5: split-K partials ----------
// grid 2048: bh = bid & 63 (XCD-local K/V), qblk = (bid>>6)&15, split = bid>>10.
// Each block scans 16 K-tiles (half the keys), writes NORMALIZED partial O (bf16)
// + partial denominator l (f32). Combine kernel blends exactly:
// O = (l0*O0 + l1*O1)/(l0+l1). Pipeline identical to verified v4 (dbuf K,
// late-prefetch V, counted vmcnt 4->2->0).
__global__ __launch_bounds__(256) void attn_kernel(const unsigned short* __restrict__ Q,
                                                   const unsigned short* __restrict__ Kb,
                                                   const unsigned short* __restrict__ Vtb,
                                                   unsigned short* __restrict__ Op,
                                                   float* __restrict__ lp) {
    const int bh    = blockIdx.x & 63;
    const int qblk  = (blockIdx.x >> 6) & 15;
    const int split = blockIdx.x >> 10;
    const int b = bh >> 4, h = bh & 15;
    const int tid = threadIdx.x, lane = tid & 63, w = tid >> 6;
    const int quad = lane >> 4, l16 = lane & 15;
    const int sw = l16 & 7;

    __shared__ __align__(16) unsigned short smem[20480];   // 40 KB
    unsigned short* Vts = smem + 8192;                     // [64 dh][swz 64 key]
    unsigned short* Psw = smem + 12288 + w * 2048;         // per-wave [32 q][swz 64 key]

    const size_t qrow0 = (size_t)b * 2048 + (size_t)qblk * 128 + w * 32;
    const int hcol = h * 64;

    // Q fragment loads first: oldest vmem ops, drained by the first vmcnt(4)
    bf16x8 qfr[2][2];
#pragma unroll
    for (int qf = 0; qf < 2; qf++)
#pragma unroll
        for (int kp = 0; kp < 2; kp++)
            qfr[qf][kp] = *(const bf16x8*)(Q + (qrow0 + qf * 16 + l16) * 1024 +
                                           hcol + kp * 32 + quad * 8);

    // this split's half of the K/V stream
    const unsigned short* ksrc = Kb  + (size_t)bh * 131072 + (size_t)split * 16 * 4096;
    const unsigned short* vsrc = Vtb + (size_t)bh * 131072 + (size_t)split * 16 * 4096;

    // prologue: stage K(0) -> buf0, V(0) -> Vts
    async_copy16(ksrc + tid * 8,        smem + tid * 8);
    async_copy16(ksrc + 2048 + tid * 8, smem + 2048 + tid * 8);
    async_copy16(vsrc + tid * 8,        Vts + tid * 8);
    async_copy16(vsrc + 2048 + tid * 8, Vts + 2048 + tid * 8);

    f32x4 acc[4][2];
#pragma unroll
    for (int df = 0; df < 4; df++)
#pragma unroll
        for (int qf = 0; qf < 2; qf++) acc[df][qf] = (f32x4){0.f, 0.f, 0.f, 0.f};
    float l_[2] = {0.f, 0.f};   // in-lane partial sums; cross-quad reduce at end

    for (int kt = 0; kt < 16; ++kt) {
        unsigned short* Ks = (kt & 1) ? (smem + 4096) : smem;   // current K buffer
        if (kt < 15) {
            unsigned short* Kd = (kt & 1) ? smem : (smem + 4096);
            const unsigned short* kg = ksrc + (size_t)(kt + 1) * 4096;
            async_copy16(kg + tid * 8,        Kd + tid * 8);
            async_copy16(kg + 2048 + tid * 8, Kd + 2048 + tid * 8);
            asm volatile("s_waitcnt vmcnt(4)" ::: "memory");    // K(kt) landed
        } else {
            asm volatile("s_waitcnt vmcnt(2)" ::: "memory");    // K(15) landed
        }
        asm volatile("s_barrier" ::: "memory");

        // S^T[64 key][32 q] = K Q^T
        f32x4 s[4][2];
#pragma unroll
        for (int mf = 0; mf < 4; mf++)
#pragma unroll
            for (int qf = 0; qf < 2; qf++) s[mf][qf] = (f32x4){0.f, 0.f, 0.f, 0.f};
        __builtin_amdgcn_s_setprio(1);
#pragma unroll
        for (int kp = 0; kp < 2; kp++) {
#pragma unroll
            for (int mf = 0; mf < 4; mf++) {
                bf16x8 kf = *(const bf16x8*)&Ks[(mf * 16 + l16) * 64 +
                                                (((kp * 4 + quad) ^ sw) << 3)];
#pragma unroll
                for (int qf = 0; qf < 2; qf++)
                    s[mf][qf] = __builtin_amdgcn_mfma_f32_16x16x32_bf16(kf, qfr[qf][kp],
                                                                        s[mf][qf], 0, 0, 0);
            }
        }
        __builtin_amdgcn_s_setprio(0);

        // p = exp2(s); accumulate in-lane row sums; trunc-pack into Psw
#pragma unroll
        for (int mf = 0; mf < 4; mf++)
#pragma unroll
            for (int qf = 0; qf < 2; qf++) {
                float e0 = exp2f(s[mf][qf][0]);
                float e1 = exp2f(s[mf][qf][1]);
                float e2 = exp2f(s[mf][qf][2]);
                float e3 = exp2f(s[mf][qf][3]);
                l_[qf] += (e0 + e1) + (e2 + e3);
                *(uint2*)&Psw[(qf * 16 + l16) * 64 +
                              (((mf * 2 + (quad >> 1)) ^ sw) << 3) + ((quad & 1) << 2)] =
                    make_uint2(pkbf_t(e1, e0), pkbf_t(e3, e2));
            }
        asm volatile("s_waitcnt lgkmcnt(0)" ::: "memory");

        if (kt < 15) {
            asm volatile("s_waitcnt vmcnt(2)" ::: "memory");    // V(kt) landed
        } else {
            asm volatile("s_waitcnt vmcnt(0)" ::: "memory");
        }
        asm volatile("s_barrier" ::: "memory");

        // out^T[64 dh][32 q] += V^T P^T
        __builtin_amdgcn_s_setprio(1);
#pragma unroll
        for (int kp = 0; kp < 2; kp++) {
            bf16x8 pf[2];
#pragma unroll
            for (int qf = 0; qf < 2; qf++)
                pf[qf] = *(const bf16x8*)&Psw[(qf * 16 + l16) * 64 +
                                              (((kp * 4 + quad) ^ sw) << 3)];
#pragma unroll
            for (int df = 0; df < 4; df++) {
                bf16x8 vf = *(const bf16x8*)&Vts[(df * 16 + l16) * 64 +
                                                 (((kp * 4 + quad) ^ sw) << 3)];
#pragma unroll
                for (int qf = 0; qf < 2; qf++)
                    acc[df][qf] = __builtin_amdgcn_mfma_f32_16x16x32_bf16(vf, pf[qf],
                                                                          acc[df][qf], 0, 0, 0);
            }
        }
        __builtin_amdgcn_s_setprio(0);

        asm volatile("s_barrier" ::: "memory");
        if (kt < 15) {
            const unsigned short* vg = vsrc + (size_t)(kt + 1) * 4096;
            async_copy16(vg + tid * 8,        Vts + tid * 8);
            async_copy16(vg + 2048 + tid * 8, Vts + 2048 + tid * 8);
        }
    }

    // row-sum reduction across quads (keys were split 4 ways within the wave)
#pragma unroll
    for (int qf = 0; qf < 2; qf++) {
        l_[qf] += __shfl_xor(l_[qf], 16, 64);
        l_[qf] += __shfl_xor(l_[qf], 32, 64);
    }

    // store partial denominators: lane group quad==0 covers q = w*32+qf*16+l16
    if (quad == 0) {
#pragma unroll
        for (int qf = 0; qf < 2; qf++)
            lp[(size_t)split * 131072 + (size_t)bh * 2048 + qblk * 128 + w * 32 +
               qf * 16 + l16] = l_[qf];
    }

    // epilogue: normalize, transpose through LDS, coalesced bf16 store of partial O
    __syncthreads();
    float inv[2] = {1.f / l_[0], 1.f / l_[1]};
    unsigned short* Ls = smem;   // [64 dh][128 q] stride 130
#pragma unroll
    for (int df = 0; df < 4; df++)
#pragma unroll
        for (int qf = 0; qf < 2; qf++)
#pragma unroll
            for (int r = 0; r < 4; r++) {
                int dh = df * 16 + quad * 4 + r;
                int q  = w * 32 + qf * 16 + l16;
                Ls[dh * 130 + q] =
                    (unsigned short)((__float_as_uint(acc[df][qf][r] * inv[qf]) + 0x8000u) >> 16);
            }
    __syncthreads();
    int q = tid >> 1, dh0 = (tid & 1) * 32;
    size_t obase = (size_t)split * 8388608 +
                   ((size_t)b * 2048 + (size_t)qblk * 128 + q) * 1024 + hcol + dh0;
#pragma unroll
    for (int c = 0; c < 4; c++) {
        us8 o;
#pragma unroll
        for (int j = 0; j < 8; j++) o[j] = Ls[(dh0 + c * 8 + j) * 130 + q];
        *(us8*)(Op + obase + c * 8) = o;
    }
}

// ---------- combine split-K partials: O = w0*O0 + w1*O1, w_s = l_s/(l0+l1) ----------
__global__ __launch_bounds__(256) void attn_combine(const unsigned short* __restrict__ Op,
                                                    const float* __restrict__ lp,
                                                    unsigned short* __restrict__ O) {
    const int row = blockIdx.x;          // 0..8191
    const int tid = threadIdx.x;
    const int col = tid * 4;
    const int b = row >> 11, t2 = row & 2047;
    const int h = col >> 6;
    const int bh = b * 16 + h;
    const float l0 = lp[(size_t)bh * 2048 + t2];
    const float l1 = lp[131072 + (size_t)bh * 2048 + t2];
    const float inv = 1.f / (l0 + l1);
    const float w0 = l0 * inv, w1 = l1 * inv;
    const size_t idx = (size_t)row * 1024 + col;
    us4 a = *(const us4*)(Op + idx);
    us4 c = *(const us4*)(Op + 8388608 + idx);
    us4 o;
#pragma unroll
    for (int j = 0; j < 4; j++) o[j] = f2bf(w0 * bf2f(a[j]) + w1 * bf2f(c[j]));
    *(us4*)(O + idx) = o;
}

// ---------- launch ----------
extern "C" void kernel_launch(void* const* d_in, const int* in_sizes, int n_in,
                              void* d_out, int out_size, void* d_ws, size_t ws_size,
                              hipStream_t stream) {
    const float* x     = (const float*)d_in[0];
    const float* ln1_g = (const float*)d_in[1];
    const float* ln1_b = (const float*)d_in[2];
    const float* ln2_g = (const float*)d_in[3];
    const float* ln2_b = (const float*)d_in[4];
    const float* wq = (const float*)d_in[5];
    const float* bq = (const float*)d_in[6];
    const float* wk = (const float*)d_in[7];
    const float* bk = (const float*)d_in[8];
    const float* wv = (const float*)d_in[9];
    const float* bv = (const float*)d_in[10];
    const float* wo = (const float*)d_in[11];
    const float* bo = (const float*)d_in[12];
    const float* w1 = (const float*)d_in[13];
    const float* b1 = (const float*)d_in[14];
    const float* w2 = (const float*)d_in[15];
    const float* b2 = (const float*)d_in[16];

    const size_t MB = 1u << 20;
    char* ws = (char*)d_ws;
    unsigned short* wqkvb = (unsigned short*)(ws + 0 * MB);   // [3072,1024] bf16, 6 MB
    unsigned short* wob  = (unsigned short*)(ws + 6 * MB);
    unsigned short* w1b  = (unsigned short*)(ws + 8 * MB);
    unsigned short* w2b  = (unsigned short*)(ws + 16 * MB);
    unsigned short* hb   = (unsigned short*)(ws + 24 * MB);   // LN1 out, later attn out
    unsigned short* qkvb = (unsigned short*)(ws + 40 * MB);   // Q | K-blocked | V^T-blocked
    unsigned short* qb   = qkvb;
    unsigned short* kblk = qkvb + 8388608;
    unsigned short* vtblk= qkvb + 16777216;
    float*          x1   = (float*)(ws + 56 * MB);            // overlays kblk+vtblk (dead)
    unsigned short* h2b  = (unsigned short*)(ws + 40 * MB);   // overlays qb (dead)
    unsigned short* ff1b = (unsigned short*)(ws + 88 * MB);   // 64 MB
    float*          bqkv = (float*)(ws + 151 * MB);           // [3072] fp32 (inside ff1b, dead then)
    // attn split-K partials live inside the ff1b region (dead during attention):
    unsigned short* attO = (unsigned short*)(ws + 88 * MB);   // 2 x 16 MiB bf16
    float*          attL = (float*)(ws + 88 * MB + 33554432); // 2 x 0.5 MiB f32

    const int D = 1024, FF = 4096, Mrows = 8192;

    cvt_bf16<<<(D * D / 4 + 255) / 256, 256, 0, stream>>>(wq, wqkvb,               D * D / 4);
    cvt_bf16<<<(D * D / 4 + 255) / 256, 256, 0, stream>>>(wk, wqkvb + D * D,       D * D / 4);
    cvt_bf16<<<(D * D / 4 + 255) / 256, 256, 0, stream>>>(wv, wqkvb + 2 * D * D,   D * D / 4);
    cvt_bf16<<<(D * D / 4 + 255) / 256, 256, 0, stream>>>(wo, wob, D * D / 4);
    cvt_bf16<<<(FF * D / 4 + 255) / 256, 256, 0, stream>>>(w1, w1b, FF * D / 4);
    cvt_bf16<<<(FF * D / 4 + 255) / 256, 256, 0, stream>>>(w2, w2b, FF * D / 4);

    hipMemcpyAsync(bqkv,            bq, D * sizeof(float), hipMemcpyDeviceToDevice, stream);
    hipMemcpyAsync(bqkv + D,        bk, D * sizeof(float), hipMemcpyDeviceToDevice, stream);
    hipMemcpyAsync(bqkv + 2 * D,    bv, D * sizeof(float), hipMemcpyDeviceToDevice, stream);

    ln_bf16<<<Mrows, 256, 0, stream>>>(x, ln1_g, ln1_b, hb);

    // fused QKV projection
    dim3 gQKV(3 * D / BN, Mrows / BM);
    gemm_nt<6><<<gQKV, 256, 0, stream>>>(hb, wqkvb, bqkv, nullptr, qkvb, D, D);

    // split-K attention: 2048 blocks (bh x qblk x 2 splits), then combine
    attn_kernel<<<2048, 256, 0, stream>>>(qb, kblk, vtblk, attO, attL);
    attn_combine<<<Mrows, 256, 0, stream>>>(attO, attL, hb);

    dim3 gD(D / BN, Mrows / BM);
    gemm_nt<2><<<gD, 256, 0, stream>>>(hb, wob, bo, x, x1, D, D);           // O + resid

    ln_bf16<<<Mrows, 256, 0, stream>>>(x1, ln2_g, ln2_b, h2b);

    dim3 gFF(FF / BN, Mrows / BM);
    gemm_nt<1><<<gFF, 256, 0, stream>>>(h2b, w1b, b1, nullptr, ff1b, FF, D);  // FF1+gelu

    gemm_nt<2><<<gD, 256, 0, stream>>>(ff1b, w2b, b2, x1, (float*)d_out, D, FF);  // FF2
}

// Round 8
// 588.350 us; speedup vs baseline: 1.0708x; 1.0472x over previous
//
#include <hip/hip_runtime.h>
#include <cstdint>
#include <cstddef>

// ---------- types ----------
typedef __attribute__((ext_vector_type(8))) __bf16 bf16x8;
typedef __attribute__((ext_vector_type(4))) float f32x4;
typedef __attribute__((ext_vector_type(8))) unsigned short us8;
typedef __attribute__((ext_vector_type(4))) unsigned short us4;

__device__ inline unsigned short f2bf(float f) {
    unsigned int u = __float_as_uint(f);
    u += 0x7fffu + ((u >> 16) & 1u);   // RNE
    return (unsigned short)(u >> 16);
}

// pack two f32 -> two bf16 by truncation (1 instr); |rel err| < 2^-8, fine for P
__device__ inline unsigned int pkbf_t(float hi, float lo) {
    return __builtin_amdgcn_perm(__float_as_uint(hi), __float_as_uint(lo), 0x07060302u);
}

// raw 2^x: skip the OCML denormal-guard libcall (inputs bounded; subnormal
// results contribute 0 to softmax anyway). 1 instr vs ~6.
__device__ inline float exp2_raw(float x) {
    float r;
    asm("v_exp_f32 %0, %1" : "=v"(r) : "v"(x));
    return r;
}

__device__ inline void async_copy16(const void* g, void* l) {
    __builtin_amdgcn_global_load_lds(
        (const __attribute__((address_space(1))) unsigned int*)g,
        (__attribute__((address_space(3))) unsigned int*)l, 16, 0, 0);
}

// ---------- fp32 -> bf16 convert ----------
__global__ __launch_bounds__(256) void cvt_bf16(const float* __restrict__ in,
                                                unsigned short* __restrict__ out, int n4) {
    int i = blockIdx.x * 256 + threadIdx.x;
    if (i < n4) {
        float4 v = ((const float4*)in)[i];
        us4 o;
        o[0] = f2bf(v.x); o[1] = f2bf(v.y); o[2] = f2bf(v.z); o[3] = f2bf(v.w);
        ((us4*)out)[i] = o;
    }
}

// ---------- layernorm (fp32 in, bf16 out) ----------
__global__ __launch_bounds__(256) void ln_bf16(const float* __restrict__ X,
                                               const float* __restrict__ g,
                                               const float* __restrict__ b,
                                               unsigned short* __restrict__ out) {
    int row = blockIdx.x;
    int t = threadIdx.x;
    float4 v = ((const float4*)(X + (size_t)row * 1024))[t];
    float s  = v.x + v.y + v.z + v.w;
    float s2 = v.x * v.x + v.y * v.y + v.z * v.z + v.w * v.w;
#pragma unroll
    for (int m = 1; m < 64; m <<= 1) {
        s  += __shfl_xor(s, m, 64);
        s2 += __shfl_xor(s2, m, 64);
    }
    __shared__ float red[8];
    int w = t >> 6, l = t & 63;
    if (l == 0) { red[w] = s; red[4 + w] = s2; }
    __syncthreads();
    s  = red[0] + red[1] + red[2] + red[3];
    s2 = red[4] + red[5] + red[6] + red[7];
    float mu  = s * (1.0f / 1024.0f);
    float var = s2 * (1.0f / 1024.0f) - mu * mu;
    float rs  = rsqrtf(var + 1e-5f);
    int c = t * 4;
    float4 gv = *(const float4*)(g + c);
    float4 bv = *(const float4*)(b + c);
    us4 o;
    o[0] = f2bf((v.x - mu) * rs * gv.x + bv.x);
    o[1] = f2bf((v.y - mu) * rs * gv.y + bv.y);
    o[2] = f2bf((v.z - mu) * rs * gv.z + bv.z);
    o[3] = f2bf((v.w - mu) * rs * gv.w + bv.w);
    *(us4*)(out + (size_t)row * 1024 + c) = o;
}

// ---------- NT GEMM (round-5 verified best): 128x128, BK=32, dist-2 pipeline ----------
// triple-buffered LDS (48 KB, 3 blocks/CU); at iter kt: vmcnt(8) waits tile kt
// (issued 2 iters ago), barrier, stage kt+2 into buf[(kt+2)%3], ds_read buf[kt%3],
// MFMA. One barrier per K-step. XCD-chunked block swizzle.
// EPI: 1 gelu(bias)->bf16 ; 2 bias+resid->fp32 ; 6 fused QKV epilogue.
#define BM 128
#define BN 128
#define BK 32

template <int EPI>
__global__ __launch_bounds__(256) void gemm_nt(const unsigned short* __restrict__ A,
                                               const unsigned short* __restrict__ B,
                                               const float* __restrict__ bias,
                                               const float* __restrict__ resid,
                                               void* __restrict__ Cout, int N, int K) {
    __shared__ __align__(16) unsigned short As[3][BM * BK];
    __shared__ __align__(16) unsigned short Bs[3][BN * BK];
    const int tid = threadIdx.x;
    const int lane = tid & 63, w = tid >> 6;
    const int quad = lane >> 4, l16 = lane & 15;
    const int wr = w >> 1, wc = w & 1;

    const int gx = gridDim.x;
    const int nwg = gx * gridDim.y;
    int wg = blockIdx.y * gx + blockIdx.x;
    if (!(nwg & 7)) wg = (wg & 7) * (nwg >> 3) + (wg >> 3);
    const size_t bm = (size_t)(wg / gx) * BM;
    const size_t bn = (size_t)(wg % gx) * BN;

#define STAGE(buf, kt)                                                        \
    {                                                                         \
        const int koff = (kt)*BK;                                             \
        _Pragma("unroll") for (int i = 0; i < 2; i++) {                       \
            int e = (i * 256 + tid) * 8;                                      \
            int r = e >> 5, c = e & 31;                                       \
            async_copy16(A + (bm + r) * K + koff + c, &As[buf][e]);           \
            async_copy16(B + (bn + r) * K + koff + c, &Bs[buf][e]);           \
        }                                                                     \
    }

    f32x4 acc[4][4];
#pragma unroll
    for (int i = 0; i < 4; i++)
#pragma unroll
        for (int j = 0; j < 4; j++) acc[i][j] = (f32x4){0.f, 0.f, 0.f, 0.f};

    const int nk = K / BK;

    STAGE(0, 0);
    STAGE(1, 1);

    for (int kt = 0; kt < nk; ++kt) {
        const int cur = kt % 3;
        if (kt + 1 < nk) {
            asm volatile("s_waitcnt vmcnt(8)" ::: "memory");
        } else {
            asm volatile("s_waitcnt vmcnt(0)" ::: "memory");
        }
        asm volatile("s_barrier" ::: "memory");

        if (kt + 2 < nk) {
            const int nxt2 = (kt + 2) % 3;
            STAGE(nxt2, kt + 2);
        }

        bf16x8 af[4], bfr[4];
#pragma unroll
        for (int mt = 0; mt < 4; mt++)
            af[mt] = *(const bf16x8*)&As[cur][(wr * 64 + mt * 16 + l16) * BK + quad * 8];
#pragma unroll
        for (int nt = 0; nt < 4; nt++)
            bfr[nt] = *(const bf16x8*)&Bs[cur][(wc * 64 + nt * 16 + l16) * BK + quad * 8];

        __builtin_amdgcn_s_setprio(1);
#pragma unroll
        for (int mt = 0; mt < 4; mt++)
#pragma unroll
            for (int nt = 0; nt < 4; nt++)
                acc[mt][nt] = __builtin_amdgcn_mfma_f32_16x16x32_bf16(af[mt], bfr[nt],
                                                                      acc[mt][nt], 0, 0, 0);
        __builtin_amdgcn_s_setprio(0);
        __builtin_amdgcn_sched_barrier(0);
    }
#undef STAGE

#pragma unroll
    for (int mt = 0; mt < 4; mt++) {
#pragma unroll
        for (int nt = 0; nt < 4; nt++) {
#pragma unroll
            for (int r = 0; r < 4; r++) {
                size_t row = bm + wr * 64 + mt * 16 + quad * 4 + r;
                size_t col = bn + wc * 64 + nt * 16 + l16;
                float v = acc[mt][nt][r] + bias[col];
                if (EPI == 1) {
                    v = 0.5f * v * (1.0f + erff(v * 0.70710678118654752f));
                    ((unsigned short*)Cout)[row * N + col] = f2bf(v);
                } else if (EPI == 2) {
                    ((float*)Cout)[row * N + col] = v + resid[row * N + col];
                } else if (EPI == 6) {
                    int sel = (int)(bn >> 10);
                    if (sel == 0) {
                        ((unsigned short*)Cout)[row * 1024 + col] =
                            f2bf(v * 0.18033688011112042f);  // 0.125*log2(e)
                    } else {
                        int key = (int)row & 2047;
                        int bh  = (((int)row >> 11) << 4) | (((int)col >> 6) & 15);
                        int dh  = (int)col & 63;
                        size_t addr;
                        if (sel == 1)
                            addr = 8388608 + (size_t)bh * 131072 +
                                   (size_t)(key >> 6) * 4096 + (size_t)(key & 63) * 64 +
                                   ((((dh >> 3) ^ (key & 7))) << 3) + (dh & 7);
                        else
                            addr = 16777216 + (size_t)bh * 131072 +
                                   (size_t)(key >> 6) * 4096 + (size_t)dh * 64 +
                                   (((((key >> 3) & 7) ^ (dh & 7))) << 3) + (key & 7);
                        ((unsigned short*)Cout)[addr] = f2bf(v);
                    }
                }
            }
        }
    }
}

// ---------- flash attention v6: raw v_exp + l-via-MFMA ----------
// grid 1024: bh = bid & 63 (qblocks of a bh stay on one XCD -> K/V L2-local),
// qblk = bid >> 6. Pipeline = verified v4: dbuf K, late-prefetch V, counted
// vmcnt 4->2->0, raw s_barrier.
// VALU cuts: (1) inline-asm v_exp_f32 (no OCML guard); (2) denominator l
// computed by an extra MFMA with ones-A (D[row][q] = sum_k P[k][q], identical
// across rows/quads) -> removes 24 adds/tile + the cross-quad shfl reduce.
__global__ __launch_bounds__(256) void attn_kernel(const unsigned short* __restrict__ Q,
                                                   const unsigned short* __restrict__ Kb,
                                                   const unsigned short* __restrict__ Vtb,
                                                   unsigned short* __restrict__ O) {
    const int bh   = blockIdx.x & 63;
    const int qblk = blockIdx.x >> 6;
    const int b = bh >> 4, h = bh & 15;
    const int tid = threadIdx.x, lane = tid & 63, w = tid >> 6;
    const int quad = lane >> 4, l16 = lane & 15;
    const int sw = l16 & 7;

    __shared__ __align__(16) unsigned short smem[20480];   // 40 KB
    unsigned short* Vts = smem + 8192;                     // [64 dh][swz 64 key]
    unsigned short* Psw = smem + 12288 + w * 2048;         // per-wave [32 q][swz 64 key]

    const size_t qrow0 = (size_t)b * 2048 + (size_t)qblk * 128 + w * 32;
    const int hcol = h * 64;

    // Q fragment loads first: oldest vmem ops, drained by the first vmcnt(4)
    bf16x8 qfr[2][2];
#pragma unroll
    for (int qf = 0; qf < 2; qf++)
#pragma unroll
        for (int kp = 0; kp < 2; kp++)
            qfr[qf][kp] = *(const bf16x8*)(Q + (qrow0 + qf * 16 + l16) * 1024 +
                                           hcol + kp * 32 + quad * 8);

    const unsigned short* ksrc = Kb  + (size_t)bh * 131072;
    const unsigned short* vsrc = Vtb + (size_t)bh * 131072;

    // prologue: stage K(0) -> buf0, V(0) -> Vts
    async_copy16(ksrc + tid * 8,        smem + tid * 8);
    async_copy16(ksrc + 2048 + tid * 8, smem + 2048 + tid * 8);
    async_copy16(vsrc + tid * 8,        Vts + tid * 8);
    async_copy16(vsrc + 2048 + tid * 8, Vts + 2048 + tid * 8);

    // ones A-fragment for the denominator MFMA
    us8 one_us;
#pragma unroll
    for (int j = 0; j < 8; j++) one_us[j] = 0x3F80;        // bf16 1.0
    const bf16x8 ones = *(const bf16x8*)&one_us;

    f32x4 acc[4][2];
#pragma unroll
    for (int df = 0; df < 4; df++)
#pragma unroll
        for (int qf = 0; qf < 2; qf++) acc[df][qf] = (f32x4){0.f, 0.f, 0.f, 0.f};
    f32x4 acc_l[2] = {(f32x4){0.f, 0.f, 0.f, 0.f}, (f32x4){0.f, 0.f, 0.f, 0.f}};

    for (int kt = 0; kt < 32; ++kt) {
        unsigned short* Ks = (kt & 1) ? (smem + 4096) : smem;   // current K buffer
        if (kt < 31) {
            unsigned short* Kd = (kt & 1) ? smem : (smem + 4096);
            const unsigned short* kg = ksrc + (size_t)(kt + 1) * 4096;
            async_copy16(kg + tid * 8,        Kd + tid * 8);
            async_copy16(kg + 2048 + tid * 8, Kd + 2048 + tid * 8);
            asm volatile("s_waitcnt vmcnt(4)" ::: "memory");    // K(kt) landed
        } else {
            asm volatile("s_waitcnt vmcnt(2)" ::: "memory");    // K(31) landed
        }
        asm volatile("s_barrier" ::: "memory");

        // S^T[64 key][32 q] = K Q^T
        f32x4 s[4][2];
#pragma unroll
        for (int mf = 0; mf < 4; mf++)
#pragma unroll
            for (int qf = 0; qf < 2; qf++) s[mf][qf] = (f32x4){0.f, 0.f, 0.f, 0.f};
        __builtin_amdgcn_s_setprio(1);
#pragma unroll
        for (int kp = 0; kp < 2; kp++) {
#pragma unroll
            for (int mf = 0; mf < 4; mf++) {
                bf16x8 kf = *(const bf16x8*)&Ks[(mf * 16 + l16) * 64 +
                                                (((kp * 4 + quad) ^ sw) << 3)];
#pragma unroll
                for (int qf = 0; qf < 2; qf++)
                    s[mf][qf] = __builtin_amdgcn_mfma_f32_16x16x32_bf16(kf, qfr[qf][kp],
                                                                        s[mf][qf], 0, 0, 0);
            }
        }
        __builtin_amdgcn_s_setprio(0);

        // p = exp2(s) (raw v_exp); trunc-pack into Psw (no VALU row-sum)
#pragma unroll
        for (int mf = 0; mf < 4; mf++)
#pragma unroll
            for (int qf = 0; qf < 2; qf++) {
                float e0 = exp2_raw(s[mf][qf][0]);
                float e1 = exp2_raw(s[mf][qf][1]);
                float e2 = exp2_raw(s[mf][qf][2]);
                float e3 = exp2_raw(s[mf][qf][3]);
                *(uint2*)&Psw[(qf * 16 + l16) * 64 +
                              (((mf * 2 + (quad >> 1)) ^ sw) << 3) + ((quad & 1) << 2)] =
                    make_uint2(pkbf_t(e1, e0), pkbf_t(e3, e2));
            }
        asm volatile("s_waitcnt lgkmcnt(0)" ::: "memory");

        if (kt < 31) {
            asm volatile("s_waitcnt vmcnt(2)" ::: "memory");    // V(kt) landed
        } else {
            asm volatile("s_waitcnt vmcnt(0)" ::: "memory");
        }
        asm volatile("s_barrier" ::: "memory");

        // out^T[64 dh][32 q] += V^T P^T ; denominator row via ones-MFMA
        __builtin_amdgcn_s_setprio(1);
#pragma unroll
        for (int kp = 0; kp < 2; kp++) {
            bf16x8 pf[2];
#pragma unroll
            for (int qf = 0; qf < 2; qf++) {
                pf[qf] = *(const bf16x8*)&Psw[(qf * 16 + l16) * 64 +
                                              (((kp * 4 + quad) ^ sw) << 3)];
                acc_l[qf] = __builtin_amdgcn_mfma_f32_16x16x32_bf16(ones, pf[qf],
                                                                    acc_l[qf], 0, 0, 0);
            }
#pragma unroll
            for (int df = 0; df < 4; df++) {
                bf16x8 vf = *(const bf16x8*)&Vts[(df * 16 + l16) * 64 +
                                                 (((kp * 4 + quad) ^ sw) << 3)];
#pragma unroll
                for (int qf = 0; qf < 2; qf++)
                    acc[df][qf] = __builtin_amdgcn_mfma_f32_16x16x32_bf16(vf, pf[qf],
                                                                          acc[df][qf], 0, 0, 0);
            }
        }
        __builtin_amdgcn_s_setprio(0);

        asm volatile("s_barrier" ::: "memory");
        if (kt < 31) {
            const unsigned short* vg = vsrc + (size_t)(kt + 1) * 4096;
            async_copy16(vg + tid * 8,        Vts + tid * 8);
            async_copy16(vg + 2048 + tid * 8, Vts + 2048 + tid * 8);
        }
    }

    // epilogue: normalize, transpose through LDS, coalesced bf16 store.
    // acc_l rows are all identical (ones-A) -> inv uniform across quads.
    __syncthreads();
    float inv[2] = {1.f / acc_l[0][0], 1.f / acc_l[1][0]};
    unsigned short* Ls = smem;   // [64 dh][128 q] stride 130
#pragma unroll
    for (int df = 0; df < 4; df++)
#pragma unroll
        for (int qf = 0; qf < 2; qf++)
#pragma unroll
            for (int r = 0; r < 4; r++) {
                int dh = df * 16 + quad * 4 + r;
                int q  = w * 32 + qf * 16 + l16;
                Ls[dh * 130 + q] =
                    (unsigned short)((__float_as_uint(acc[df][qf][r] * inv[qf]) + 0x8000u) >> 16);
            }
    __syncthreads();
    int q = tid >> 1, dh0 = (tid & 1) * 32;
    size_t obase = ((size_t)b * 2048 + (size_t)qblk * 128 + q) * 1024 + hcol + dh0;
#pragma unroll
    for (int c = 0; c < 4; c++) {
        us8 o;
#pragma unroll
        for (int j = 0; j < 8; j++) o[j] = Ls[(dh0 + c * 8 + j) * 130 + q];
        *(us8*)(O + obase + c * 8) = o;
    }
}

// ---------- launch ----------
extern "C" void kernel_launch(void* const* d_in, const int* in_sizes, int n_in,
                              void* d_out, int out_size, void* d_ws, size_t ws_size,
                              hipStream_t stream) {
    const float* x     = (const float*)d_in[0];
    const float* ln1_g = (const float*)d_in[1];
    const float* ln1_b = (const float*)d_in[2];
    const float* ln2_g = (const float*)d_in[3];
    const float* ln2_b = (const float*)d_in[4];
    const float* wq = (const float*)d_in[5];
    const float* bq = (const float*)d_in[6];
    const float* wk = (const float*)d_in[7];
    const float* bk = (const float*)d_in[8];
    const float* wv = (const float*)d_in[9];
    const float* bv = (const float*)d_in[10];
    const float* wo = (const float*)d_in[11];
    const float* bo = (const float*)d_in[12];
    const float* w1 = (const float*)d_in[13];
    const float* b1 = (const float*)d_in[14];
    const float* w2 = (const float*)d_in[15];
    const float* b2 = (const float*)d_in[16];

    const size_t MB = 1u << 20;
    char* ws = (char*)d_ws;
    unsigned short* wqkvb = (unsigned short*)(ws + 0 * MB);   // [3072,1024] bf16, 6 MB
    unsigned short* wob  = (unsigned short*)(ws + 6 * MB);
    unsigned short* w1b  = (unsigned short*)(ws + 8 * MB);
    unsigned short* w2b  = (unsigned short*)(ws + 16 * MB);
    unsigned short* hb   = (unsigned short*)(ws + 24 * MB);   // LN1 out, later attn out
    unsigned short* qkvb = (unsigned short*)(ws + 40 * MB);   // Q | K-blocked | V^T-blocked
    unsigned short* qb   = qkvb;
    unsigned short* kblk = qkvb + 8388608;
    unsigned short* vtblk= qkvb + 16777216;
    float*          x1   = (float*)(ws + 56 * MB);            // overlays kblk+vtblk (dead)
    unsigned short* h2b  = (unsigned short*)(ws + 40 * MB);   // overlays qb (dead)
    unsigned short* ff1b = (unsigned short*)(ws + 88 * MB);   // 64 MB
    float*          bqkv = (float*)(ws + 151 * MB);           // [3072] fp32 (inside ff1b, dead then)

    const int D = 1024, FF = 4096, Mrows = 8192;

    cvt_bf16<<<(D * D / 4 + 255) / 256, 256, 0, stream>>>(wq, wqkvb,               D * D / 4);
    cvt_bf16<<<(D * D / 4 + 255) / 256, 256, 0, stream>>>(wk, wqkvb + D * D,       D * D / 4);
    cvt_bf16<<<(D * D / 4 + 255) / 256, 256, 0, stream>>>(wv, wqkvb + 2 * D * D,   D * D / 4);
    cvt_bf16<<<(D * D / 4 + 255) / 256, 256, 0, stream>>>(wo, wob, D * D / 4);
    cvt_bf16<<<(FF * D / 4 + 255) / 256, 256, 0, stream>>>(w1, w1b, FF * D / 4);
    cvt_bf16<<<(FF * D / 4 + 255) / 256, 256, 0, stream>>>(w2, w2b, FF * D / 4);

    hipMemcpyAsync(bqkv,            bq, D * sizeof(float), hipMemcpyDeviceToDevice, stream);
    hipMemcpyAsync(bqkv + D,        bk, D * sizeof(float), hipMemcpyDeviceToDevice, stream);
    hipMemcpyAsync(bqkv + 2 * D,    bv, D * sizeof(float), hipMemcpyDeviceToDevice, stream);

    ln_bf16<<<Mrows, 256, 0, stream>>>(x, ln1_g, ln1_b, hb);

    // fused QKV projection
    dim3 gQKV(3 * D / BN, Mrows / BM);
    gemm_nt<6><<<gQKV, 256, 0, stream>>>(hb, wqkvb, bqkv, nullptr, qkvb, D, D);

    attn_kernel<<<1024, 256, 0, stream>>>(qb, kblk, vtblk, hb);

    dim3 gD(D / BN, Mrows / BM);
    gemm_nt<2><<<gD, 256, 0, stream>>>(hb, wob, bo, x, x1, D, D);           // O + resid

    ln_bf16<<<Mrows, 256, 0, stream>>>(x1, ln2_g, ln2_b, h2b);

    dim3 gFF(FF / BN, Mrows / BM);
    gemm_nt<1><<<gFF, 256, 0, stream>>>(h2b, w1b, b1, nullptr, ff1b, FF, D);  // FF1+gelu

    gemm_nt<2><<<gD, 256, 0, stream>>>(ff1b, w2b, b2, x1, (float*)d_out, D, FF);  // FF2
}

// Round 9
// 583.926 us; speedup vs baseline: 1.0789x; 1.0076x over previous
//
#include <hip/hip_runtime.h>
#include <cstdint>
#include <cstddef>

// ---------- types ----------
typedef __attribute__((ext_vector_type(8))) __bf16 bf16x8;
typedef __attribute__((ext_vector_type(4))) float f32x4;
typedef __attribute__((ext_vector_type(8))) unsigned short us8;
typedef __attribute__((ext_vector_type(4))) unsigned short us4;

__device__ inline unsigned short f2bf(float f) {
    unsigned int u = __float_as_uint(f);
    u += 0x7fffu + ((u >> 16) & 1u);   // RNE
    return (unsigned short)(u >> 16);
}

// pack two f32 -> two bf16 by truncation (1 instr); |rel err| < 2^-8, fine for P
__device__ inline unsigned int pkbf_t(float hi, float lo) {
    return __builtin_amdgcn_perm(__float_as_uint(hi), __float_as_uint(lo), 0x07060302u);
}

// raw 2^x: skip the OCML denormal-guard libcall (inputs bounded; subnormal
// results contribute 0 to softmax anyway). 1 instr vs ~6.
__device__ inline float exp2_raw(float x) {
    float r;
    asm("v_exp_f32 %0, %1" : "=v"(r) : "v"(x));
    return r;
}

__device__ inline void async_copy16(const void* g, void* l) {
    __builtin_amdgcn_global_load_lds(
        (const __attribute__((address_space(1))) unsigned int*)g,
        (__attribute__((address_space(3))) unsigned int*)l, 16, 0, 0);
}

// ---------- fp32 -> bf16 convert ----------
__global__ __launch_bounds__(256) void cvt_bf16(const float* __restrict__ in,
                                                unsigned short* __restrict__ out, int n4) {
    int i = blockIdx.x * 256 + threadIdx.x;
    if (i < n4) {
        float4 v = ((const float4*)in)[i];
        us4 o;
        o[0] = f2bf(v.x); o[1] = f2bf(v.y); o[2] = f2bf(v.z); o[3] = f2bf(v.w);
        ((us4*)out)[i] = o;
    }
}

// ---------- layernorm (fp32 in, bf16 out) ----------
__global__ __launch_bounds__(256) void ln_bf16(const float* __restrict__ X,
                                               const float* __restrict__ g,
                                               const float* __restrict__ b,
                                               unsigned short* __restrict__ out) {
    int row = blockIdx.x;
    int t = threadIdx.x;
    float4 v = ((const float4*)(X + (size_t)row * 1024))[t];
    float s  = v.x + v.y + v.z + v.w;
    float s2 = v.x * v.x + v.y * v.y + v.z * v.z + v.w * v.w;
#pragma unroll
    for (int m = 1; m < 64; m <<= 1) {
        s  += __shfl_xor(s, m, 64);
        s2 += __shfl_xor(s2, m, 64);
    }
    __shared__ float red[8];
    int w = t >> 6, l = t & 63;
    if (l == 0) { red[w] = s; red[4 + w] = s2; }
    __syncthreads();
    s  = red[0] + red[1] + red[2] + red[3];
    s2 = red[4] + red[5] + red[6] + red[7];
    float mu  = s * (1.0f / 1024.0f);
    float var = s2 * (1.0f / 1024.0f) - mu * mu;
    float rs  = rsqrtf(var + 1e-5f);
    int c = t * 4;
    float4 gv = *(const float4*)(g + c);
    float4 bv = *(const float4*)(b + c);
    us4 o;
    o[0] = f2bf((v.x - mu) * rs * gv.x + bv.x);
    o[1] = f2bf((v.y - mu) * rs * gv.y + bv.y);
    o[2] = f2bf((v.z - mu) * rs * gv.z + bv.z);
    o[3] = f2bf((v.w - mu) * rs * gv.w + bv.w);
    *(us4*)(out + (size_t)row * 1024 + c) = o;
}

// ---------- NT GEMM: 128x128, BK=32, dist-2 pipeline + T2 LDS swizzle ----------
// triple-buffered LDS (48 KB, 3 blocks/CU); at iter kt: vmcnt(8) waits tile kt
// (issued 2 iters ago), barrier, stage kt+2 into buf[(kt+2)%3], ds_read buf[kt%3],
// MFMA. One barrier per K-step. XCD-chunked block swizzle.
// T2 swizzle (both-sides, rule #21): rows are 64 B = 4 chunks of 16 B.
//   f(r) = (r>>1)&3; LDS chunk j of row r holds GLOBAL chunk j^f(r)
//   (linear LDS dest for global_load_lds, pre-swizzled global source);
//   reads fetch chunk quad^f(row). Fragment rows = 16*m + l16 so
//   f(row) = (l16>>1)&3 -> per-lane constant swq. Maps 16 lanes onto
//   8 (parity,chunk) bank-slots 2-to-1 => 2-way = conflict-free (m136).
// EPI: 1 gelu(bias)->bf16 ; 2 bias+resid->fp32 ; 6 fused QKV epilogue.
#define BM 128
#define BN 128
#define BK 32

template <int EPI>
__global__ __launch_bounds__(256) void gemm_nt(const unsigned short* __restrict__ A,
                                               const unsigned short* __restrict__ B,
                                               const float* __restrict__ bias,
                                               const float* __restrict__ resid,
                                               void* __restrict__ Cout, int N, int K) {
    __shared__ __align__(16) unsigned short As[3][BM * BK];
    __shared__ __align__(16) unsigned short Bs[3][BN * BK];
    const int tid = threadIdx.x;
    const int lane = tid & 63, w = tid >> 6;
    const int quad = lane >> 4, l16 = lane & 15;
    const int wr = w >> 1, wc = w & 1;
    const int swq = quad ^ ((l16 >> 1) & 3);   // swizzled read chunk

    const int gx = gridDim.x;
    const int nwg = gx * gridDim.y;
    int wg = blockIdx.y * gx + blockIdx.x;
    if (!(nwg & 7)) wg = (wg & 7) * (nwg >> 3) + (wg >> 3);
    const size_t bm = (size_t)(wg / gx) * BM;
    const size_t bn = (size_t)(wg % gx) * BN;

#define STAGE(buf, kt)                                                        \
    {                                                                         \
        const int koff = (kt)*BK;                                             \
        _Pragma("unroll") for (int i = 0; i < 2; i++) {                       \
            int e = (i * 256 + tid) * 8;                                      \
            int r = e >> 5;                                                   \
            int csw = (((e >> 3) & 3) ^ ((r >> 1) & 3)) << 3;                 \
            async_copy16(A + (bm + r) * K + koff + csw, &As[buf][e]);         \
            async_copy16(B + (bn + r) * K + koff + csw, &Bs[buf][e]);         \
        }                                                                     \
    }

    f32x4 acc[4][4];
#pragma unroll
    for (int i = 0; i < 4; i++)
#pragma unroll
        for (int j = 0; j < 4; j++) acc[i][j] = (f32x4){0.f, 0.f, 0.f, 0.f};

    const int nk = K / BK;

    STAGE(0, 0);
    STAGE(1, 1);

    for (int kt = 0; kt < nk; ++kt) {
        const int cur = kt % 3;
        if (kt + 1 < nk) {
            asm volatile("s_waitcnt vmcnt(8)" ::: "memory");
        } else {
            asm volatile("s_waitcnt vmcnt(0)" ::: "memory");
        }
        asm volatile("s_barrier" ::: "memory");

        if (kt + 2 < nk) {
            const int nxt2 = (kt + 2) % 3;
            STAGE(nxt2, kt + 2);
        }

        bf16x8 af[4], bfr[4];
#pragma unroll
        for (int mt = 0; mt < 4; mt++)
            af[mt] = *(const bf16x8*)&As[cur][(wr * 64 + mt * 16 + l16) * BK + swq * 8];
#pragma unroll
        for (int nt = 0; nt < 4; nt++)
            bfr[nt] = *(const bf16x8*)&Bs[cur][(wc * 64 + nt * 16 + l16) * BK + swq * 8];

        __builtin_amdgcn_s_setprio(1);
#pragma unroll
        for (int mt = 0; mt < 4; mt++)
#pragma unroll
            for (int nt = 0; nt < 4; nt++)
                acc[mt][nt] = __builtin_amdgcn_mfma_f32_16x16x32_bf16(af[mt], bfr[nt],
                                                                      acc[mt][nt], 0, 0, 0);
        __builtin_amdgcn_s_setprio(0);
        __builtin_amdgcn_sched_barrier(0);
    }
#undef STAGE

#pragma unroll
    for (int mt = 0; mt < 4; mt++) {
#pragma unroll
        for (int nt = 0; nt < 4; nt++) {
#pragma unroll
            for (int r = 0; r < 4; r++) {
                size_t row = bm + wr * 64 + mt * 16 + quad * 4 + r;
                size_t col = bn + wc * 64 + nt * 16 + l16;
                float v = acc[mt][nt][r] + bias[col];
                if (EPI == 1) {
                    v = 0.5f * v * (1.0f + erff(v * 0.70710678118654752f));
                    ((unsigned short*)Cout)[row * N + col] = f2bf(v);
                } else if (EPI == 2) {
                    ((float*)Cout)[row * N + col] = v + resid[row * N + col];
                } else if (EPI == 6) {
                    int sel = (int)(bn >> 10);
                    if (sel == 0) {
                        ((unsigned short*)Cout)[row * 1024 + col] =
                            f2bf(v * 0.18033688011112042f);  // 0.125*log2(e)
                    } else {
                        int key = (int)row & 2047;
                        int bh  = (((int)row >> 11) << 4) | (((int)col >> 6) & 15);
                        int dh  = (int)col & 63;
                        size_t addr;
                        if (sel == 1)
                            addr = 8388608 + (size_t)bh * 131072 +
                                   (size_t)(key >> 6) * 4096 + (size_t)(key & 63) * 64 +
                                   ((((dh >> 3) ^ (key & 7))) << 3) + (dh & 7);
                        else
                            addr = 16777216 + (size_t)bh * 131072 +
                                   (size_t)(key >> 6) * 4096 + (size_t)dh * 64 +
                                   (((((key >> 3) & 7) ^ (dh & 7))) << 3) + (key & 7);
                        ((unsigned short*)Cout)[addr] = f2bf(v);
                    }
                }
            }
        }
    }
}

// ---------- flash attention v6: raw v_exp + l-via-MFMA ----------
// grid 1024: bh = bid & 63 (qblocks of a bh stay on one XCD -> K/V L2-local),
// qblk = bid >> 6. Pipeline = verified v4: dbuf K, late-prefetch V, counted
// vmcnt 4->2->0, raw s_barrier.
// VALU cuts: (1) inline-asm v_exp_f32 (no OCML guard); (2) denominator l
// computed by an extra MFMA with ones-A (D[row][q] = sum_k P[k][q], identical
// across rows/quads) -> removes 24 adds/tile + the cross-quad shfl reduce.
__global__ __launch_bounds__(256) void attn_kernel(const unsigned short* __restrict__ Q,
                                                   const unsigned short* __restrict__ Kb,
                                                   const unsigned short* __restrict__ Vtb,
                                                   unsigned short* __restrict__ O) {
    const int bh   = blockIdx.x & 63;
    const int qblk = blockIdx.x >> 6;
    const int b = bh >> 4, h = bh & 15;
    const int tid = threadIdx.x, lane = tid & 63, w = tid >> 6;
    const int quad = lane >> 4, l16 = lane & 15;
    const int sw = l16 & 7;

    __shared__ __align__(16) unsigned short smem[20480];   // 40 KB
    unsigned short* Vts = smem + 8192;                     // [64 dh][swz 64 key]
    unsigned short* Psw = smem + 12288 + w * 2048;         // per-wave [32 q][swz 64 key]

    const size_t qrow0 = (size_t)b * 2048 + (size_t)qblk * 128 + w * 32;
    const int hcol = h * 64;

    // Q fragment loads first: oldest vmem ops, drained by the first vmcnt(4)
    bf16x8 qfr[2][2];
#pragma unroll
    for (int qf = 0; qf < 2; qf++)
#pragma unroll
        for (int kp = 0; kp < 2; kp++)
            qfr[qf][kp] = *(const bf16x8*)(Q + (qrow0 + qf * 16 + l16) * 1024 +
                                           hcol + kp * 32 + quad * 8);

    const unsigned short* ksrc = Kb  + (size_t)bh * 131072;
    const unsigned short* vsrc = Vtb + (size_t)bh * 131072;

    // prologue: stage K(0) -> buf0, V(0) -> Vts
    async_copy16(ksrc + tid * 8,        smem + tid * 8);
    async_copy16(ksrc + 2048 + tid * 8, smem + 2048 + tid * 8);
    async_copy16(vsrc + tid * 8,        Vts + tid * 8);
    async_copy16(vsrc + 2048 + tid * 8, Vts + 2048 + tid * 8);

    // ones A-fragment for the denominator MFMA
    us8 one_us;
#pragma unroll
    for (int j = 0; j < 8; j++) one_us[j] = 0x3F80;        // bf16 1.0
    const bf16x8 ones = *(const bf16x8*)&one_us;

    f32x4 acc[4][2];
#pragma unroll
    for (int df = 0; df < 4; df++)
#pragma unroll
        for (int qf = 0; qf < 2; qf++) acc[df][qf] = (f32x4){0.f, 0.f, 0.f, 0.f};
    f32x4 acc_l[2] = {(f32x4){0.f, 0.f, 0.f, 0.f}, (f32x4){0.f, 0.f, 0.f, 0.f}};

    for (int kt = 0; kt < 32; ++kt) {
        unsigned short* Ks = (kt & 1) ? (smem + 4096) : smem;   // current K buffer
        if (kt < 31) {
            unsigned short* Kd = (kt & 1) ? smem : (smem + 4096);
            const unsigned short* kg = ksrc + (size_t)(kt + 1) * 4096;
            async_copy16(kg + tid * 8,        Kd + tid * 8);
            async_copy16(kg + 2048 + tid * 8, Kd + 2048 + tid * 8);
            asm volatile("s_waitcnt vmcnt(4)" ::: "memory");    // K(kt) landed
        } else {
            asm volatile("s_waitcnt vmcnt(2)" ::: "memory");    // K(31) landed
        }
        asm volatile("s_barrier" ::: "memory");

        // S^T[64 key][32 q] = K Q^T
        f32x4 s[4][2];
#pragma unroll
        for (int mf = 0; mf < 4; mf++)
#pragma unroll
            for (int qf = 0; qf < 2; qf++) s[mf][qf] = (f32x4){0.f, 0.f, 0.f, 0.f};
        __builtin_amdgcn_s_setprio(1);
#pragma unroll
        for (int kp = 0; kp < 2; kp++) {
#pragma unroll
            for (int mf = 0; mf < 4; mf++) {
                bf16x8 kf = *(const bf16x8*)&Ks[(mf * 16 + l16) * 64 +
                                                (((kp * 4 + quad) ^ sw) << 3)];
#pragma unroll
                for (int qf = 0; qf < 2; qf++)
                    s[mf][qf] = __builtin_amdgcn_mfma_f32_16x16x32_bf16(kf, qfr[qf][kp],
                                                                        s[mf][qf], 0, 0, 0);
            }
        }
        __builtin_amdgcn_s_setprio(0);

        // p = exp2(s) (raw v_exp); trunc-pack into Psw (no VALU row-sum)
#pragma unroll
        for (int mf = 0; mf < 4; mf++)
#pragma unroll
            for (int qf = 0; qf < 2; qf++) {
                float e0 = exp2_raw(s[mf][qf][0]);
                float e1 = exp2_raw(s[mf][qf][1]);
                float e2 = exp2_raw(s[mf][qf][2]);
                float e3 = exp2_raw(s[mf][qf][3]);
                *(uint2*)&Psw[(qf * 16 + l16) * 64 +
                              (((mf * 2 + (quad >> 1)) ^ sw) << 3) + ((quad & 1) << 2)] =
                    make_uint2(pkbf_t(e1, e0), pkbf_t(e3, e2));
            }
        asm volatile("s_waitcnt lgkmcnt(0)" ::: "memory");

        if (kt < 31) {
            asm volatile("s_waitcnt vmcnt(2)" ::: "memory");    // V(kt) landed
        } else {
            asm volatile("s_waitcnt vmcnt(0)" ::: "memory");
        }
        asm volatile("s_barrier" ::: "memory");

        // out^T[64 dh][32 q] += V^T P^T ; denominator row via ones-MFMA
        __builtin_amdgcn_s_setprio(1);
#pragma unroll
        for (int kp = 0; kp < 2; kp++) {
            bf16x8 pf[2];
#pragma unroll
            for (int qf = 0; qf < 2; qf++) {
                pf[qf] = *(const bf16x8*)&Psw[(qf * 16 + l16) * 64 +
                                              (((kp * 4 + quad) ^ sw) << 3)];
                acc_l[qf] = __builtin_amdgcn_mfma_f32_16x16x32_bf16(ones, pf[qf],
                                                                    acc_l[qf], 0, 0, 0);
            }
#pragma unroll
            for (int df = 0; df < 4; df++) {
                bf16x8 vf = *(const bf16x8*)&Vts[(df * 16 + l16) * 64 +
                                                 (((kp * 4 + quad) ^ sw) << 3)];
#pragma unroll
                for (int qf = 0; qf < 2; qf++)
                    acc[df][qf] = __builtin_amdgcn_mfma_f32_16x16x32_bf16(vf, pf[qf],
                                                                          acc[df][qf], 0, 0, 0);
            }
        }
        __builtin_amdgcn_s_setprio(0);

        asm volatile("s_barrier" ::: "memory");
        if (kt < 31) {
            const unsigned short* vg = vsrc + (size_t)(kt + 1) * 4096;
            async_copy16(vg + tid * 8,        Vts + tid * 8);
            async_copy16(vg + 2048 + tid * 8, Vts + 2048 + tid * 8);
        }
    }

    // epilogue: normalize, transpose through LDS, coalesced bf16 store.
    // acc_l rows are all identical (ones-A) -> inv uniform across quads.
    __syncthreads();
    float inv[2] = {1.f / acc_l[0][0], 1.f / acc_l[1][0]};
    unsigned short* Ls = smem;   // [64 dh][128 q] stride 130
#pragma unroll
    for (int df = 0; df < 4; df++)
#pragma unroll
        for (int qf = 0; qf < 2; qf++)
#pragma unroll
            for (int r = 0; r < 4; r++) {
                int dh = df * 16 + quad * 4 + r;
                int q  = w * 32 + qf * 16 + l16;
                Ls[dh * 130 + q] =
                    (unsigned short)((__float_as_uint(acc[df][qf][r] * inv[qf]) + 0x8000u) >> 16);
            }
    __syncthreads();
    int q = tid >> 1, dh0 = (tid & 1) * 32;
    size_t obase = ((size_t)b * 2048 + (size_t)qblk * 128 + q) * 1024 + hcol + dh0;
#pragma unroll
    for (int c = 0; c < 4; c++) {
        us8 o;
#pragma unroll
        for (int j = 0; j < 8; j++) o[j] = Ls[(dh0 + c * 8 + j) * 130 + q];
        *(us8*)(O + obase + c * 8) = o;
    }
}

// ---------- launch ----------
extern "C" void kernel_launch(void* const* d_in, const int* in_sizes, int n_in,
                              void* d_out, int out_size, void* d_ws, size_t ws_size,
                              hipStream_t stream) {
    const float* x     = (const float*)d_in[0];
    const float* ln1_g = (const float*)d_in[1];
    const float* ln1_b = (const float*)d_in[2];
    const float* ln2_g = (const float*)d_in[3];
    const float* ln2_b = (const float*)d_in[4];
    const float* wq = (const float*)d_in[5];
    const float* bq = (const float*)d_in[6];
    const float* wk = (const float*)d_in[7];
    const float* bk = (const float*)d_in[8];
    const float* wv = (const float*)d_in[9];
    const float* bv = (const float*)d_in[10];
    const float* wo = (const float*)d_in[11];
    const float* bo = (const float*)d_in[12];
    const float* w1 = (const float*)d_in[13];
    const float* b1 = (const float*)d_in[14];
    const float* w2 = (const float*)d_in[15];
    const float* b2 = (const float*)d_in[16];

    const size_t MB = 1u << 20;
    char* ws = (char*)d_ws;
    unsigned short* wqkvb = (unsigned short*)(ws + 0 * MB);   // [3072,1024] bf16, 6 MB
    unsigned short* wob  = (unsigned short*)(ws + 6 * MB);
    unsigned short* w1b  = (unsigned short*)(ws + 8 * MB);
    unsigned short* w2b  = (unsigned short*)(ws + 16 * MB);
    unsigned short* hb   = (unsigned short*)(ws + 24 * MB);   // LN1 out, later attn out
    unsigned short* qkvb = (unsigned short*)(ws + 40 * MB);   // Q | K-blocked | V^T-blocked
    unsigned short* qb   = qkvb;
    unsigned short* kblk = qkvb + 8388608;
    unsigned short* vtblk= qkvb + 16777216;
    float*          x1   = (float*)(ws + 56 * MB);            // overlays kblk+vtblk (dead)
    unsigned short* h2b  = (unsigned short*)(ws + 40 * MB);   // overlays qb (dead)
    unsigned short* ff1b = (unsigned short*)(ws + 88 * MB);   // 64 MB
    float*          bqkv = (float*)(ws + 151 * MB);           // [3072] fp32 (inside ff1b, dead then)

    const int D = 1024, FF = 4096, Mrows = 8192;

    cvt_bf16<<<(D * D / 4 + 255) / 256, 256, 0, stream>>>(wq, wqkvb,               D * D / 4);
    cvt_bf16<<<(D * D / 4 + 255) / 256, 256, 0, stream>>>(wk, wqkvb + D * D,       D * D / 4);
    cvt_bf16<<<(D * D / 4 + 255) / 256, 256, 0, stream>>>(wv, wqkvb + 2 * D * D,   D * D / 4);
    cvt_bf16<<<(D * D / 4 + 255) / 256, 256, 0, stream>>>(wo, wob, D * D / 4);
    cvt_bf16<<<(FF * D / 4 + 255) / 256, 256, 0, stream>>>(w1, w1b, FF * D / 4);
    cvt_bf16<<<(FF * D / 4 + 255) / 256, 256, 0, stream>>>(w2, w2b, FF * D / 4);

    hipMemcpyAsync(bqkv,            bq, D * sizeof(float), hipMemcpyDeviceToDevice, stream);
    hipMemcpyAsync(bqkv + D,        bk, D * sizeof(float), hipMemcpyDeviceToDevice, stream);
    hipMemcpyAsync(bqkv + 2 * D,    bv, D * sizeof(float), hipMemcpyDeviceToDevice, stream);

    ln_bf16<<<Mrows, 256, 0, stream>>>(x, ln1_g, ln1_b, hb);

    // fused QKV projection
    dim3 gQKV(3 * D / BN, Mrows / BM);
    gemm_nt<6><<<gQKV, 256, 0, stream>>>(hb, wqkvb, bqkv, nullptr, qkvb, D, D);

    attn_kernel<<<1024, 256, 0, stream>>>(qb, kblk, vtblk, hb);

    dim3 gD(D / BN, Mrows / BM);
    gemm_nt<2><<<gD, 256, 0, stream>>>(hb, wob, bo, x, x1, D, D);           // O + resid

    ln_bf16<<<Mrows, 256, 0, stream>>>(x1, ln2_g, ln2_b, h2b);

    dim3 gFF(FF / BN, Mrows / BM);
    gemm_nt<1><<<gFF, 256, 0, stream>>>(h2b, w1b, b1, nullptr, ff1b, FF, D);  // FF1+gelu

    gemm_nt<2><<<gD, 256, 0, stream>>>(ff1b, w2b, b2, x1, (float*)d_out, D, FF);  // FF2
}